// Round 2
// baseline (272.211 us; speedup 1.0000x reference)
//
#include <hip/hip_runtime.h>
#include <math.h>

#define BATCH 64
#define ADIM  1152
#define BDIM  32
#define SLICE 512                 // BDIM*POSE floats per (bt, a) row
#define CHUNKS 16
#define ROWS  72                  // rows per block = ADIM/CHUNKS
#define RPW   18                  // rows per wave (4 waves/block)
#define EPSQ  1e-6f
#define SPART_ITER ((size_t)BATCH * CHUNKS * SLICE)

typedef float v4f __attribute__((ext_vector_type(4)));

// ---------------------------------------------------------------------------
// Shared helpers.
// Fragment layout everywhere: v4f slot s of a 512-float capsule vector holds
// b = s>>2, poses 4*(s&3)+k. A wave's lane l owns slots l (b=l>>2) and
// 64+l (b=16+(l>>2)).
// ---------------------------------------------------------------------------

// Reduce 16 chunk partials of one batch, then squash. n[pose]=sum_b s[b][pose]^2
// reduced over the 16 lanes sharing l&3 via xor-4..32 shuffles.
__device__ __forceinline__ void squash_from(const float* sp, int lane,
                                            v4f& sA, v4f& sB, v4f& fac) {
    const v4f* spv = (const v4f*)sp;
    sA = (v4f){0.f, 0.f, 0.f, 0.f};
    sB = (v4f){0.f, 0.f, 0.f, 0.f};
#pragma unroll
    for (int c = 0; c < CHUNKS; ++c) {
        sA += spv[c * 128 + lane];
        sB += spv[c * 128 + 64 + lane];
    }
    v4f nq = sA * sA + sB * sB;
#pragma unroll
    for (int off = 4; off <= 32; off <<= 1) {
        nq.x += __shfl_xor(nq.x, off, 64);
        nq.y += __shfl_xor(nq.y, off, 64);
        nq.z += __shfl_xor(nq.z, off, 64);
        nq.w += __shfl_xor(nq.w, off, 64);
    }
    fac.x = sqrtf(nq.x + EPSQ) / (1.f + nq.x);
    fac.y = sqrtf(nq.y + EPSQ) / (1.f + nq.y);
    fac.z = sqrtf(nq.z + EPSQ) / (1.f + nq.z);
    fac.w = sqrtf(nq.w + EPSQ) / (1.f + nq.w);
}

// cross-wave reduce of per-wave partials; wv0 writes slots lane / 64+lane
__device__ __forceinline__ void reduce_write(v4f* red, int lane, int wv,
                                             v4f ra, v4f rb, float* dst) {
    __syncthreads();
    if (wv == 3) { red[lane] = ra; red[64 + lane] = rb; }
    __syncthreads();
    if (wv == 2) { red[lane] += ra; red[64 + lane] += rb; }
    __syncthreads();
    if (wv == 1) { red[lane] += ra; red[64 + lane] += rb; }
    __syncthreads();
    if (wv == 0) {
        v4f* sp = (v4f*)dst;
        sp[lane]      = red[lane] + ra;
        sp[64 + lane] = red[64 + lane] + rb;
    }
}

// ---------------------------------------------------------------------------
// Pass 0: stream v fp32 with CACHED loads (151 MB -> allocates in the 256 MB
// L3, so iter passes re-read it without touching HBM). Accumulate
// s0 = sum_a softmax(logits)*v. No bf16 tile, no psum global.
// ---------------------------------------------------------------------------
__global__ __launch_bounds__(256) void pass0(
    const float* __restrict__ v,       // [BATCH][ADIM][BDIM][POSE]
    const float* __restrict__ logits,  // [ADIM][BDIM]
    float* __restrict__ s0)            // [BATCH][CHUNKS][SLICE]
{
    const int bt    = blockIdx.x >> 4;
    const int chunk = blockIdx.x & 15;
    const int t     = threadIdx.x;
    const int lane  = t & 63;
    const int wv    = t >> 6;
    const int bq    = lane >> 2;
    const int a0    = chunk * ROWS;
    const int r0    = wv * RPW;

    __shared__ float w_sh[ROWS * BDIM];   // softmax(logits) weights  9 KB
    __shared__ v4f   red[128];            // cross-wave reduce        2 KB

    if (t < ROWS) {
        const float* lr = logits + (size_t)(a0 + t) * BDIM;
        float e[BDIM];
        float s = 0.f;
#pragma unroll
        for (int b = 0; b < BDIM; ++b) { e[b] = __expf(lr[b]); s += e[b]; }
        float rd = 1.f / s;
#pragma unroll
        for (int b = 0; b < BDIM; ++b) w_sh[t * BDIM + b] = e[b] * rd;
    }
    __syncthreads();

    const v4f* vg = (const v4f*)(v + ((size_t)bt * ADIM + a0 + r0) * SLICE);
    v4f acc0 = (v4f){0.f, 0.f, 0.f, 0.f};
    v4f acc1 = (v4f){0.f, 0.f, 0.f, 0.f};

    v4f fA[6], fB[6];
#pragma unroll
    for (int u = 0; u < 6; ++u) fA[u] = vg[lane + 64 * u];

#pragma unroll
    for (int kk = 0; kk < 6; ++kk) {
        v4f* cur = (kk & 1) ? fB : fA;
        v4f* nxt = (kk & 1) ? fA : fB;
        if (kk + 1 < 6) {
#pragma unroll
            for (int u = 0; u < 6; ++u)
                nxt[u] = vg[lane + 64 * ((kk + 1) * 6 + u)];
        }
#pragma unroll
        for (int u = 0; u < 6; ++u) {
            const int j  = kk * 6 + u;
            const int rw = r0 + (j >> 1);        // row within chunk
            if ((j & 1) == 0) acc0 += w_sh[rw * BDIM + bq] * cur[u];       // b=bq
            else              acc1 += w_sh[rw * BDIM + 16 + bq] * cur[u];  // b=16+bq
        }
    }

    reduce_write(red, lane, wv, acc0, acc1,
                 s0 + ((size_t)bt * CHUNKS + chunk) * SLICE);
}

// ---------------------------------------------------------------------------
// Iteration pass (used for iters 1 and 2). psum = sum_{j<nprev} squash(s_j)
// recomputed redundantly per block from L2/L3-resident s_part (identical
// arithmetic in every block -> bitwise-identical psum). v re-read fp32 (L3).
// ---------------------------------------------------------------------------
__global__ __launch_bounds__(256) void iter_pass(
    const float* __restrict__ v,
    const float* __restrict__ logits,
    const float* __restrict__ s_part,  // [3][BATCH][CHUNKS][SLICE] (regions 0..nprev-1 valid)
    float* __restrict__ s_next,        // [BATCH][CHUNKS][SLICE]
    int nprev)
{
    const int bt    = blockIdx.x >> 4;
    const int chunk = blockIdx.x & 15;
    const int t     = threadIdx.x;
    const int lane  = t & 63;
    const int wv    = t >> 6;
    const int bq    = lane >> 2;
    const int a0    = chunk * ROWS;
    const int r0    = wv * RPW;

    __shared__ v4f red[128];           // 2 KB

    v4f pA = (v4f){0.f, 0.f, 0.f, 0.f};
    v4f pB = (v4f){0.f, 0.f, 0.f, 0.f};
    for (int j = 0; j < nprev; ++j) {
        v4f sA, sB, fac;
        squash_from(s_part + (size_t)j * SPART_ITER +
                    (size_t)bt * CHUNKS * SLICE, lane, sA, sB, fac);
        pA += fac * sA;
        pB += fac * sB;
    }

    const v4f*  vr  = (const v4f*)(v + ((size_t)bt * ADIM + a0 + r0) * SLICE);
    const float* lgr = logits + (size_t)(a0 + r0) * BDIM;

    v4f acc0 = (v4f){0.f, 0.f, 0.f, 0.f};
    v4f acc1 = (v4f){0.f, 0.f, 0.f, 0.f};

    // 1-row software prefetch; the shfl/exp chain of row r covers row r+1's loads
    v4f  vaN = vr[lane], vbN = vr[64 + lane];
    float b0N = lgr[bq], b1N = lgr[16 + bq];
#pragma unroll
    for (int r = 0; r < RPW; ++r) {
        v4f  va = vaN, vb = vbN;
        float b0 = b0N, b1 = b1N;
        if (r + 1 < RPW) {
            vaN = vr[(r + 1) * 128 + lane];
            vbN = vr[(r + 1) * 128 + 64 + lane];
            b0N = lgr[(r + 1) * BDIM + bq];
            b1N = lgr[(r + 1) * BDIM + 16 + bq];
        }
        float d0 = pA.x * va.x + pA.y * va.y + pA.z * va.z + pA.w * va.w;
        float d1 = pB.x * vb.x + pB.y * vb.y + pB.z * vb.z + pB.w * vb.w;
        d0 += __shfl_xor(d0, 1, 64); d0 += __shfl_xor(d0, 2, 64);
        d1 += __shfl_xor(d1, 1, 64); d1 += __shfl_xor(d1, 2, 64);
        float e0 = __expf(b0 + d0);
        float e1 = __expf(b1 + d1);
        float uu = e0 + e1;
#pragma unroll
        for (int off = 4; off <= 32; off <<= 1)
            uu += __shfl_xor(uu, off, 64);
        float rdc = __builtin_amdgcn_rcpf(uu);
        acc0 += (e0 * rdc) * va;
        acc1 += (e1 * rdc) * vb;
    }

    reduce_write(red, lane, wv, acc0, acc1,
                 s_next + ((size_t)bt * CHUNKS + chunk) * SLICE);
}

// final: reduce iter-2 chunk partials, squash, emit a_out (8192) ++ p (32768)
__global__ __launch_bounds__(512) void final_out(
    const float* __restrict__ s_part2,  // [bt][CHUNKS][SLICE]
    float* __restrict__ out)
{
    const int bt = blockIdx.x;
    const int t  = threadIdx.x;        // t = bc*16 + pose
    const int pose = t & 15;

    __shared__ float sq[SLICE];
    __shared__ float ns[16];

    float sv = 0.f;
#pragma unroll
    for (int c = 0; c < CHUNKS; ++c)
        sv += s_part2[((size_t)bt * CHUNKS + c) * SLICE + t];

    sq[t] = sv * sv;
    __syncthreads();
    if (t < 16) {
        float a = 0.f;
        for (int b2 = 0; b2 < BDIM; ++b2) a += sq[b2 * 16 + t];
        ns[t] = a;
    }
    __syncthreads();
    float n = ns[pose];
    float pv = sqrtf(n + EPSQ) / (1.f + n) * sv;

    out[8192 + (size_t)bt * SLICE + t] = pv;
    sq[t] = pv * pv;
    __syncthreads();
    // a_out[bt][b2][p2] = sqrt(sum_p1 p[b2][p1*4+p2]^2)
    if (t < 128) {
        const int b2 = t >> 2, p2 = t & 3;
        float a = 0.f;
#pragma unroll
        for (int p1 = 0; p1 < 4; ++p1) a += sq[b2 * 16 + p1 * 4 + p2];
        out[(size_t)bt * 128 + t] = sqrtf(a);
    }
}

extern "C" void kernel_launch(void* const* d_in, const int* in_sizes, int n_in,
                              void* d_out, int out_size, void* d_ws, size_t ws_size,
                              hipStream_t stream) {
    const float* v      = (const float*)d_in[1];   // (64,1152,32,4,4,1)
    const float* logits = (const float*)d_in[2];   // (1,1152,32,1,1,1)
    float* out    = (float*)d_out;
    float* s_part = (float*)d_ws;                  // 3 * 2 MB, written before read

    pass0<<<dim3(BATCH * CHUNKS), dim3(256), 0, stream>>>(
        v, logits, s_part);
    iter_pass<<<dim3(BATCH * CHUNKS), dim3(256), 0, stream>>>(
        v, logits, s_part, s_part + 1 * SPART_ITER, 1);
    iter_pass<<<dim3(BATCH * CHUNKS), dim3(256), 0, stream>>>(
        v, logits, s_part, s_part + 2 * SPART_ITER, 2);
    final_out<<<dim3(BATCH), dim3(512), 0, stream>>>(
        s_part + 2 * SPART_ITER, out);
}